// Round 3
// baseline (156.913 us; speedup 1.0000x reference)
//
#include <hip/hip_runtime.h>

#define NN 8192
#define FIN 512
#define FO 64

typedef short bf16x8 __attribute__((ext_vector_type(8)));
typedef float f32x4 __attribute__((ext_vector_type(4)));

union AFrag { bf16x8 v; __bf16 b[8]; };

// ---------------- kernel 0: W[512][64] f32 -> WT[64][512] bf16 (LDS transpose)
__global__ __launch_bounds__(512) void wt_kernel(const float* __restrict__ W, __bf16* __restrict__ WT) {
    __shared__ float tile[64][65];
    const int k0 = blockIdx.x * 64;
    // coalesced read: 8 rounds, 512 threads cover 64k x 64f
    #pragma unroll
    for (int r = 0; r < 8; ++r) {
        const int kl = r * 8 + (threadIdx.x >> 6);
        const int f  = threadIdx.x & 63;
        tile[kl][f] = W[(size_t)(k0 + kl) * FO + f];
    }
    __syncthreads();
    // coalesced write: thread -> (f, 8 consecutive k), packed bf16 pairs
    const int f   = threadIdx.x >> 3;
    const int kk8 = (threadIdx.x & 7) * 8;
    unsigned u[4];
    #pragma unroll
    for (int h = 0; h < 4; ++h) {
        union { __bf16 b; unsigned short us; } lo, hi;
        lo.b = (__bf16)tile[kk8 + 2*h][f];
        hi.b = (__bf16)tile[kk8 + 2*h + 1][f];
        u[h] = (unsigned)lo.us | ((unsigned)hi.us << 16);
    }
    *(uint4*)(WT + (size_t)f * FIN + k0 + kk8) = make_uint4(u[0], u[1], u[2], u[3]);
}

// ---------------- kernel 1: Wh = x@W (bf16 MFMA), emit swizzled Wh + s + t ---
// whs layout: per 32-col block jb, per ft (0..3), per lane l: uint4 = 8 bf16
// B-fragment elems for mfma_f32_16x16x32_bf16.
__global__ __launch_bounds__(128) void wh_kernel(
    const float* __restrict__ x, const __bf16* __restrict__ WT,
    const float* __restrict__ a, uint4* __restrict__ whs,
    float* __restrict__ s_out, float* __restrict__ t_out)
{
    __shared__ float whlds[2][16][FO + 1];
    const int w  = threadIdx.x >> 6;
    const int l  = threadIdx.x & 63;
    const int lr = l & 15, lg = l >> 4;
    const int rb = (blockIdx.x * 2 + w) * 16;   // 16 rows per wave

    f32x4 acc[4] = {};
    const float* xr = x + (size_t)(rb + lr) * FIN;
    const __bf16* wbase[4];
    #pragma unroll
    for (int ft = 0; ft < 4; ++ft) wbase[ft] = WT + (ft*16 + lr) * FIN;

    float4 nxa = *(const float4*)(xr + lg*4);
    float4 nxb = *(const float4*)(xr + lg*4 + 16);
    for (int ks = 0; ks < 16; ++ks) {
        const int k0 = ks*32 + lg*4;
        const float4 xa = nxa, xb = nxb;
        const int kn = (ks < 15 ? ks + 1 : 15)*32 + lg*4;   // 1-deep x prefetch
        nxa = *(const float4*)(xr + kn);
        nxb = *(const float4*)(xr + kn + 16);
        AFrag af;
        af.b[0]=(__bf16)xa.x; af.b[1]=(__bf16)xa.y; af.b[2]=(__bf16)xa.z; af.b[3]=(__bf16)xa.w;
        af.b[4]=(__bf16)xb.x; af.b[5]=(__bf16)xb.y; af.b[6]=(__bf16)xb.z; af.b[7]=(__bf16)xb.w;
        #pragma unroll
        for (int ft = 0; ft < 4; ++ft) {
            union { bf16x8 v; uint2 q[2]; } bf;
            bf.q[0] = *(const uint2*)(wbase[ft] + k0);
            bf.q[1] = *(const uint2*)(wbase[ft] + k0 + 16);
            acc[ft] = __builtin_amdgcn_mfma_f32_16x16x32_bf16(af.v, bf.v, acc[ft], 0, 0, 0);
        }
    }

    #pragma unroll
    for (int ft = 0; ft < 4; ++ft)
        #pragma unroll
        for (int q = 0; q < 4; ++q)
            whlds[w][lg*4+q][ft*16+lr] = acc[ft][q];

    // s = Wh@a1, t = Wh@a2
    float sp[4] = {0,0,0,0}, tp[4] = {0,0,0,0};
    #pragma unroll
    for (int ft = 0; ft < 4; ++ft) {
        const float a1 = a[ft*16 + lr];
        const float a2 = a[FO + ft*16 + lr];
        #pragma unroll
        for (int q = 0; q < 4; ++q) { sp[q] += acc[ft][q]*a1; tp[q] += acc[ft][q]*a2; }
    }
    #pragma unroll
    for (int d = 1; d < 16; d <<= 1) {
        #pragma unroll
        for (int q = 0; q < 4; ++q) { sp[q] += __shfl_xor(sp[q], d); tp[q] += __shfl_xor(tp[q], d); }
    }
    if (lr == 0) {
        *(float4*)(s_out + rb + lg*4) = make_float4(sp[0], sp[1], sp[2], sp[3]);
        *(float4*)(t_out + rb + lg*4) = make_float4(tp[0], tp[1], tp[2], tp[3]);
    }

    __syncthreads();

    // swizzled fragment store: this block's 32 rows = column-block jb
    const int jb = blockIdx.x;
    #pragma unroll
    for (int q = 0; q < 2; ++q) {
        const int ft = w*2 + q;
        const int f  = ft*16 + lr;
        unsigned u[4];
        #pragma unroll
        for (int h = 0; h < 4; ++h) {
            const int c0 = ((h & 2) ? 16 : 0) + lg*4 + (h & 1)*2;
            union { __bf16 b; unsigned short us; } lo, hi;
            lo.b = (__bf16)whlds[c0 >> 4][c0 & 15][f];
            hi.b = (__bf16)whlds[(c0+1) >> 4][(c0+1) & 15][f];
            u[h] = (unsigned)lo.us | ((unsigned)hi.us << 16);
        }
        whs[(jb*4 + ft)*64 + l] = make_uint4(u[0], u[1], u[2], u[3]);
    }
}

// ---------------- kernel 2: fused masked-softmax attention ----------------
// 256 blocks x 512 thr: 2 row-groups(16 rows) x 4 K-waves(2048 cols, 64 iters).
// Register pipeline: adj 4-deep, t 2-deep, whs 1-deep.
__global__ __launch_bounds__(512, 4) void gat_kernel(
    const int* __restrict__ adj, const uint4* __restrict__ whs,
    const float* __restrict__ s_in, const float* __restrict__ t_in,
    float* __restrict__ out)
{
    __shared__ float red[8][16][FO];
    __shared__ float dnl[8][16];
    const int w  = threadIdx.x >> 6;   // 0..7
    const int g  = w >> 2;             // row-group 0/1
    const int kw = w & 3;              // K-split wave 0..3
    const int l  = threadIdx.x & 63;
    const int lr = l & 15, lg = l >> 4;
    const int rg = blockIdx.x;
    const int R  = rg * 32 + g * 16 + lr;
    const float sv = s_in[R];
    const int* adjr = adj + (size_t)R * NN;
    const bf16x8* wv = (const bf16x8*)whs;
    const int cbase = kw * 2048 + lg * 4;       // lane's column base
    const int jbase = kw * 64;                  // wave's first 32-col block

    f32x4 acc[4] = {};
    float dn = 0.f;

    // pipelines
    int4   pa[4][2];   // adj, 4-deep
    float4 pt[2][2];   // t,   2-deep
    bf16x8 bv[2][4];   // whs, 1-deep (double buffer)

    #pragma unroll
    for (int i = 0; i < 4; ++i) {
        const int jc = cbase + i*32;
        pa[i][0] = *(const int4*)(adjr + jc);
        pa[i][1] = *(const int4*)(adjr + jc + 16);
    }
    #pragma unroll
    for (int i = 0; i < 2; ++i) {
        const int jc = cbase + i*32;
        pt[i][0] = *(const float4*)(t_in + jc);
        pt[i][1] = *(const float4*)(t_in + jc + 16);
    }
    #pragma unroll
    for (int ft = 0; ft < 4; ++ft) bv[0][ft] = wv[(jbase*4 + ft)*64 + l];

    #pragma unroll 4
    for (int st = 0; st < 64; ++st) {
        const int sl4 = st & 3, sl2 = st & 1;
        const int4   A0 = pa[sl4][0], A1 = pa[sl4][1];
        const float4 T0 = pt[sl2][0], T1 = pt[sl2][1];

        // refill pipelines (clamped; redundant loads at tail are in-bounds)
        {
            const int ja = cbase + (st+4 < 64 ? st+4 : 63)*32;
            pa[sl4][0] = *(const int4*)(adjr + ja);
            pa[sl4][1] = *(const int4*)(adjr + ja + 16);
            const int jt = cbase + (st+2 < 64 ? st+2 : 63)*32;
            pt[sl2][0] = *(const float4*)(t_in + jt);
            pt[sl2][1] = *(const float4*)(t_in + jt + 16);
            const int jbn = jbase + (st+1 < 64 ? st+1 : 63);
            #pragma unroll
            for (int ft = 0; ft < 4; ++ft) bv[(st+1)&1][ft] = wv[(jbn*4 + ft)*64 + l];
        }

        const int   av[8] = {A0.x, A0.y, A0.z, A0.w, A1.x, A1.y, A1.z, A1.w};
        const float tv[8] = {T0.x, T0.y, T0.z, T0.w, T1.x, T1.y, T1.z, T1.w};
        float p[8];
        #pragma unroll
        for (int i = 0; i < 8; ++i) {
            float e = sv + tv[i];
            e = fmaxf(e, 0.2f * e);            // leaky_relu; |e| small -> no max-shift
            p[i] = av[i] ? __expf(e) : 0.f;
            dn += p[i];
        }
        AFrag af;
        #pragma unroll
        for (int i = 0; i < 8; ++i) af.b[i] = (__bf16)p[i];
        #pragma unroll
        for (int ft = 0; ft < 4; ++ft)
            acc[ft] = __builtin_amdgcn_mfma_f32_16x16x32_bf16(af.v, bv[st&1][ft], acc[ft], 0, 0, 0);
    }

    dn += __shfl_xor(dn, 16);
    dn += __shfl_xor(dn, 32);

    #pragma unroll
    for (int ft = 0; ft < 4; ++ft)
        #pragma unroll
        for (int q = 0; q < 4; ++q)
            red[w][lg*4+q][ft*16+lr] = acc[ft][q];
    if (l < 16) dnl[w][l] = dn;
    __syncthreads();

    // cross-wave reduce (4 K-waves per row-group) + normalize + ELU
    for (int o = threadIdx.x; o < 32*FO; o += 512) {
        const int row = o >> 6, f = o & 63;
        const int gg = row >> 4, r16 = row & 15;
        float v = 0.f, den = 0.f;
        #pragma unroll
        for (int ww = 0; ww < 4; ++ww) { v += red[gg*4+ww][r16][f]; den += dnl[gg*4+ww][r16]; }
        const float h = v / den;
        out[(size_t)(rg*32 + row) * FO + f] = (h > 0.f) ? h : (__expf(h) - 1.f);
    }
}

extern "C" void kernel_launch(void* const* d_in, const int* in_sizes, int n_in,
                              void* d_out, int out_size, void* d_ws, size_t ws_size,
                              hipStream_t stream) {
    const float* x   = (const float*)d_in[0];
    const int*   adj = (const int*)d_in[1];
    const float* W   = (const float*)d_in[2];
    const float* a   = (const float*)d_in[3];
    float* out = (float*)d_out;

    char* ws = (char*)d_ws;
    uint4*  whs = (uint4*)ws;                                // 1 MiB swizzled Wh
    __bf16* WT  = (__bf16*)(ws + (1u << 20));                // 64 KiB
    float*  s   = (float*)(ws + (1u << 20) + (1u << 16));    // 32 KiB
    float*  t   = (float*)(ws + (1u << 20) + (1u << 16) + 32768);  // 32 KiB

    wt_kernel<<<8, 512, 0, stream>>>(W, WT);
    wh_kernel<<<256, 128, 0, stream>>>(x, WT, a, whs, s, t);
    gat_kernel<<<256, 512, 0, stream>>>(adj, whs, s, t, out);
}

// Round 4
// 93.626 us; speedup vs baseline: 1.6759x; 1.6759x over previous
//
#include <hip/hip_runtime.h>

#define NN 8192
#define FIN 512
#define FO 64

typedef short bf16x8 __attribute__((ext_vector_type(8)));
typedef float f32x4 __attribute__((ext_vector_type(4)));

union AFrag { bf16x8 v; __bf16 b[8]; };

// ---------------- kernel 0: W[512][64] f32 -> WT[64][512] bf16 (LDS transpose)
__global__ __launch_bounds__(512) void wt_kernel(const float* __restrict__ W, __bf16* __restrict__ WT) {
    __shared__ float tile[64][65];
    const int k0 = blockIdx.x * 64;
    #pragma unroll
    for (int r = 0; r < 8; ++r) {
        const int kl = r * 8 + (threadIdx.x >> 6);
        const int f  = threadIdx.x & 63;
        tile[kl][f] = W[(size_t)(k0 + kl) * FO + f];
    }
    __syncthreads();
    const int f   = threadIdx.x >> 3;
    const int kk8 = (threadIdx.x & 7) * 8;
    unsigned u[4];
    #pragma unroll
    for (int h = 0; h < 4; ++h) {
        union { __bf16 b; unsigned short us; } lo, hi;
        lo.b = (__bf16)tile[kk8 + 2*h][f];
        hi.b = (__bf16)tile[kk8 + 2*h + 1][f];
        u[h] = (unsigned)lo.us | ((unsigned)hi.us << 16);
    }
    *(uint4*)(WT + (size_t)f * FIN + k0 + kk8) = make_uint4(u[0], u[1], u[2], u[3]);
}

// ---------------- kernel 1: Wh = x@W (bf16 MFMA), emit swizzled Wh + s + t ---
// whs layout: per 32-col block jb, per ft (0..3), per lane l: uint4 = 8 bf16
// B-fragment elems for mfma_f32_16x16x32_bf16. (verified by R1/R2 pass)
__global__ __launch_bounds__(128) void wh_kernel(
    const float* __restrict__ x, const __bf16* __restrict__ WT,
    const float* __restrict__ a, uint4* __restrict__ whs,
    float* __restrict__ s_out, float* __restrict__ t_out)
{
    __shared__ float whlds[2][16][FO + 1];
    const int w  = threadIdx.x >> 6;
    const int l  = threadIdx.x & 63;
    const int lr = l & 15, lg = l >> 4;
    const int rb = (blockIdx.x * 2 + w) * 16;

    f32x4 acc[4] = {};
    const float* xr = x + (size_t)(rb + lr) * FIN;
    const __bf16* wbase[4];
    #pragma unroll
    for (int ft = 0; ft < 4; ++ft) wbase[ft] = WT + (ft*16 + lr) * FIN;

    float4 nxa = *(const float4*)(xr + lg*4);
    float4 nxb = *(const float4*)(xr + lg*4 + 16);
    for (int ks = 0; ks < 16; ++ks) {
        const int k0 = ks*32 + lg*4;
        const float4 xa = nxa, xb = nxb;
        const int kn = (ks < 15 ? ks + 1 : 15)*32 + lg*4;
        nxa = *(const float4*)(xr + kn);
        nxb = *(const float4*)(xr + kn + 16);
        AFrag af;
        af.b[0]=(__bf16)xa.x; af.b[1]=(__bf16)xa.y; af.b[2]=(__bf16)xa.z; af.b[3]=(__bf16)xa.w;
        af.b[4]=(__bf16)xb.x; af.b[5]=(__bf16)xb.y; af.b[6]=(__bf16)xb.z; af.b[7]=(__bf16)xb.w;
        #pragma unroll
        for (int ft = 0; ft < 4; ++ft) {
            union { bf16x8 v; uint2 q[2]; } bf;
            bf.q[0] = *(const uint2*)(wbase[ft] + k0);
            bf.q[1] = *(const uint2*)(wbase[ft] + k0 + 16);
            acc[ft] = __builtin_amdgcn_mfma_f32_16x16x32_bf16(af.v, bf.v, acc[ft], 0, 0, 0);
        }
    }

    #pragma unroll
    for (int ft = 0; ft < 4; ++ft)
        #pragma unroll
        for (int q = 0; q < 4; ++q)
            whlds[w][lg*4+q][ft*16+lr] = acc[ft][q];

    float sp[4] = {0,0,0,0}, tp[4] = {0,0,0,0};
    #pragma unroll
    for (int ft = 0; ft < 4; ++ft) {
        const float a1 = a[ft*16 + lr];
        const float a2 = a[FO + ft*16 + lr];
        #pragma unroll
        for (int q = 0; q < 4; ++q) { sp[q] += acc[ft][q]*a1; tp[q] += acc[ft][q]*a2; }
    }
    #pragma unroll
    for (int d = 1; d < 16; d <<= 1) {
        #pragma unroll
        for (int q = 0; q < 4; ++q) { sp[q] += __shfl_xor(sp[q], d); tp[q] += __shfl_xor(tp[q], d); }
    }
    if (lr == 0) {
        *(float4*)(s_out + rb + lg*4) = make_float4(sp[0], sp[1], sp[2], sp[3]);
        *(float4*)(t_out + rb + lg*4) = make_float4(tp[0], tp[1], tp[2], tp[3]);
    }

    __syncthreads();

    const int jb = blockIdx.x;
    #pragma unroll
    for (int q = 0; q < 2; ++q) {
        const int ft = w*2 + q;
        const int f  = ft*16 + lr;
        unsigned u[4];
        #pragma unroll
        for (int h = 0; h < 4; ++h) {
            const int c0 = ((h & 2) ? 16 : 0) + lg*4 + (h & 1)*2;
            union { __bf16 b; unsigned short us; } lo, hi;
            lo.b = (__bf16)whlds[c0 >> 4][c0 & 15][f];
            hi.b = (__bf16)whlds[(c0+1) >> 4][(c0+1) & 15][f];
            u[h] = (unsigned)lo.us | ((unsigned)hi.us << 16);
        }
        whs[(jb*4 + ft)*64 + l] = make_uint4(u[0], u[1], u[2], u[3]);
    }
}

// ---------------- kernel 2: fused masked-softmax attention ----------------
// Block = 16 rows x 16 waves. Wave w streams row w's adj CONTIGUOUSLY (2KB/iter),
// computes p = adj*exp(leaky(s_i+t_j)), writes bf16 p to LDS in MFMA-fragment
// order (XOR-swizzled). After a raw lgkmcnt-barrier (vmcnt stays in flight),
// wave w ds_read_b128's its A-fragment for col-block w and MFMAs against whs.
// K-reduction across the 16 waves via LDS tree (reuses p buffers).
__global__ __launch_bounds__(1024, 4) void gat_kernel(
    const int* __restrict__ adj, const uint4* __restrict__ whs,
    const float* __restrict__ s_in, const float* __restrict__ t_in,
    float* __restrict__ out)
{
    __shared__ __align__(16) unsigned char plds[2][16384];
    __shared__ float dnl[16];
    const int w  = threadIdx.x >> 6;   // 0..15: row within tile AND reader col-block
    const int l  = threadIdx.x & 63;
    const int lr = l & 15, lg = l >> 4;
    const int rg = blockIdx.x;
    const int row = rg * 16 + w;
    const float sv = s_in[row];
    const int* adjr = adj + (size_t)row * NN;
    const bf16x8* wv = (const bf16x8*)whs;

    // writer LDS byte addrs: lane l holds cols l*4..+3 (chunk0) and 256+l*4 (chunk1)
    // fragment addr = ((jb*64 + lane')*16 + half*8) ^ ((jb&7)<<4) ^ ((lane'>>4)<<5)
    const int lane0 = w + ((l & 3) << 4);        // lane' (row=w, lg'=l&3)
    const int halfb = ((l >> 2) & 1) << 3;
    const int jbA = l >> 3, jbB = 8 + (l >> 3);
    const int wa0 = ((((jbA << 6) + lane0) << 4) + halfb) ^ ((jbA & 7) << 4) ^ ((l & 3) << 5);
    const int wa1 = ((((jbB << 6) + lane0) << 4) + halfb) ^ ((jbB & 7) << 4) ^ ((l & 3) << 5);
    // reader: wave w reads fragment jb_local = w, lane l -> 16B
    const int ra  = ((((w << 6) + l) << 4)) ^ ((w & 7) << 4) ^ ((lg & 3) << 5);

    f32x4 acc[4] = {};
    float dn = 0.f;

    // prologue: loads for it=0 (single-buffered regs; reloaded after consumption)
    int4   A0 = *(const int4*)(adjr + l*4);
    int4   A1 = *(const int4*)(adjr + 256 + l*4);
    float4 T0 = *(const float4*)(t_in + l*4);
    float4 T1 = *(const float4*)(t_in + 256 + l*4);
    bf16x8 bv[2][4];
    #pragma unroll
    for (int ft = 0; ft < 4; ++ft) bv[0][ft] = wv[(w*4 + ft)*64 + l];

    #pragma unroll 2
    for (int it = 0; it < 16; ++it) {
        const int   av[8] = {A0.x, A0.y, A0.z, A0.w, A1.x, A1.y, A1.z, A1.w};
        const float tv[8] = {T0.x, T0.y, T0.z, T0.w, T1.x, T1.y, T1.z, T1.w};

        // issue next-iter loads now; the "memory"-clobber barrier below pins
        // their ISSUE before it, and (no vmcnt in the asm) they stay in flight.
        const int cn = (it == 15) ? 0 : (it + 1) * 512;
        A0 = *(const int4*)(adjr + cn + l*4);
        A1 = *(const int4*)(adjr + cn + 256 + l*4);
        T0 = *(const float4*)(t_in + cn + l*4);
        T1 = *(const float4*)(t_in + cn + 256 + l*4);
        const int jn = ((it == 15) ? 0 : ((it + 1) * 16 + w)) * 4;
        #pragma unroll
        for (int ft = 0; ft < 4; ++ft) bv[(it + 1) & 1][ft] = wv[(jn + ft)*64 + l];

        // p = adj * exp(leaky(s+t)), packed bf16 pairs
        unsigned pk[4];
        #pragma unroll
        for (int i = 0; i < 4; ++i) {
            float e0 = sv + tv[2*i];     e0 = fmaxf(e0, 0.2f * e0);
            float e1 = sv + tv[2*i + 1]; e1 = fmaxf(e1, 0.2f * e1);
            const float p0 = av[2*i]     ? __expf(e0) : 0.f;
            const float p1 = av[2*i + 1] ? __expf(e1) : 0.f;
            dn += p0 + p1;
            union { __bf16 b; unsigned short u; } c0, c1;
            c0.b = (__bf16)p0; c1.b = (__bf16)p1;
            pk[i] = (unsigned)c0.u | ((unsigned)c1.u << 16);
        }
        *(uint2*)(plds[it & 1] + wa0) = make_uint2(pk[0], pk[1]);
        *(uint2*)(plds[it & 1] + wa1) = make_uint2(pk[2], pk[3]);

        // drain LDS only; global prefetches stay outstanding across the barrier
        asm volatile("s_waitcnt lgkmcnt(0)\n\ts_barrier" ::: "memory");

        AFrag af;
        af.v = *(const bf16x8*)(plds[it & 1] + ra);
        #pragma unroll
        for (int ft = 0; ft < 4; ++ft)
            acc[ft] = __builtin_amdgcn_mfma_f32_16x16x32_bf16(af.v, bv[it & 1][ft], acc[ft], 0, 0, 0);
    }

    // row denominator: wave w owns all of row w -> full 64-lane reduce
    #pragma unroll
    for (int d = 1; d < 64; d <<= 1) dn += __shfl_xor(dn, d);
    if (l == 0) dnl[w] = dn;

    // K-reduce acc across 16 waves: LDS tree reusing plds (32 KB)
    float* red = (float*)plds;
    #pragma unroll
    for (int h = 8; h >= 1; h >>= 1) {
        __syncthreads();
        if (w >= h && w < 2*h) {
            #pragma unroll
            for (int ft = 0; ft < 4; ++ft)
                #pragma unroll
                for (int q = 0; q < 4; ++q)
                    red[(((w - h) * 16) + ft*4 + q)*64 + l] = acc[ft][q];
        }
        __syncthreads();
        if (w < h) {
            #pragma unroll
            for (int ft = 0; ft < 4; ++ft)
                #pragma unroll
                for (int q = 0; q < 4; ++q)
                    acc[ft][q] += red[((w * 16) + ft*4 + q)*64 + l];
        }
    }

    // epilogue: wave 0 holds the 16x64 tile. C/D map: feat = ft*16+lr, m = lg*4+q
    if (w == 0) {
        #pragma unroll
        for (int ft = 0; ft < 4; ++ft) {
            #pragma unroll
            for (int q = 0; q < 4; ++q) {
                const int m = lg*4 + q;
                const float h2 = acc[ft][q] / dnl[m];
                out[(size_t)(rg*16 + m) * FO + ft*16 + lr] =
                    (h2 > 0.f) ? h2 : (__expf(h2) - 1.f);
            }
        }
    }
}

extern "C" void kernel_launch(void* const* d_in, const int* in_sizes, int n_in,
                              void* d_out, int out_size, void* d_ws, size_t ws_size,
                              hipStream_t stream) {
    const float* x   = (const float*)d_in[0];
    const int*   adj = (const int*)d_in[1];
    const float* W   = (const float*)d_in[2];
    const float* a   = (const float*)d_in[3];
    float* out = (float*)d_out;

    char* ws = (char*)d_ws;
    uint4*  whs = (uint4*)ws;                                // 1 MiB swizzled Wh
    __bf16* WT  = (__bf16*)(ws + (1u << 20));                // 64 KiB
    float*  s   = (float*)(ws + (1u << 20) + (1u << 16));    // 32 KiB
    float*  t   = (float*)(ws + (1u << 20) + (1u << 16) + 32768);  // 32 KiB

    wt_kernel<<<8, 512, 0, stream>>>(W, WT);
    wh_kernel<<<256, 128, 0, stream>>>(x, WT, a, whs, s, t);
    gat_kernel<<<512, 1024, 0, stream>>>(adj, whs, s, t, out);
}